// Round 10
// baseline (194.316 us; speedup 1.0000x reference)
//
#include <hip/hip_runtime.h>
#include <hip/hip_bf16.h>
#include <stdint.h>

#define N_NODES 50000
#define N_EDGES 800000
#define IN_CH   128
#define NEG_SLOPE 0.2f

#define E_PER 4                  // edges per fill thread (4 independent atomics in flight)
#define FILL_BLOCKS 782          // ceil(800000 / (256*4)) — fill first: starts earliest
#define PROJ_BLOCKS 782          // ceil(3125 wave-tiles / 4); each wave = 16 rows

typedef short short8 __attribute__((ext_vector_type(8)));
typedef float f32x4  __attribute__((ext_vector_type(4)));
typedef float f32x2  __attribute__((ext_vector_type(2)));

static __device__ __forceinline__ float bf_lo(uint32_t p) { return __uint_as_float(p << 16); }
static __device__ __forceinline__ float bf_hi(uint32_t p) { return __uint_as_float(p & 0xffff0000u); }
static __device__ __forceinline__ uint16_t f_to_bf(float f) {
    uint32_t u = __float_as_uint(f);
    u += 0x7fffu + ((u >> 16) & 1u);   // round-to-nearest-even
    return (uint16_t)(u >> 16);
}
static __device__ __forceinline__ float lrelu(float x) { return fmaxf(x, NEG_SLOPE * x); }

// 16-lane sum-broadcast, pure VALU via DPP butterfly — every lane ends with
// the full 16-lane (head-group) sum.  No LDS traffic.
static __device__ __forceinline__ float sum16(float x) {
    x += __uint_as_float(__builtin_amdgcn_update_dpp(0, __float_as_uint(x), 0xB1,  0xf, 0xf, true)); // quad_perm[1,0,3,2]
    x += __uint_as_float(__builtin_amdgcn_update_dpp(0, __float_as_uint(x), 0x4E,  0xf, 0xf, true)); // quad_perm[2,3,0,1]
    x += __uint_as_float(__builtin_amdgcn_update_dpp(0, __float_as_uint(x), 0x141, 0xf, 0xf, true)); // row_half_mirror
    x += __uint_as_float(__builtin_amdgcn_update_dpp(0, __float_as_uint(x), 0x140, 0xf, 0xf, true)); // row_mirror
    return x;
}

// ---------------------------------------------------------------------------
// prep: (a) swizzle Wl/Wr (f32) -> bf16 in MFMA B-fragment order;
//       (b) zero the cnt array (grid-stride).  One dispatch.
// ---------------------------------------------------------------------------
__global__ __launch_bounds__(256) void prep_kernel(
    const float* __restrict__ Wl, const float* __restrict__ Wr,
    __hip_bfloat16* __restrict__ wswz, int* __restrict__ cnt)
{
    int t = blockIdx.x * 256 + threadIdx.x;   // 64 blocks x 256 = 16384
    if (t < 4096) {
        int ct = t >> 8, rem = t & 255;
        int ch = rem >> 6, lane = rem & 63;
        int m = lane & 15, quad = lane >> 4;
        const float* W = (ct < 8) ? Wl : Wr;
        int o = ((ct & 7) << 4) + m;
        const float* src = W + (size_t)o * IN_CH + ch * 32 + quad * 8;
        short8 f;
#pragma unroll
        for (int j = 0; j < 8; ++j) f[j] = (short)f_to_bf(src[j]);
        *(short8*)((short*)wswz + (size_t)t * 8) = f;
    }
    for (int i = t; i < N_NODES; i += 64 * 256) cnt[i] = 0;
}

// ---------------------------------------------------------------------------
// mid: fused fill + proj, disjoint block ranges.  Fill FIRST (low blockIdx):
// blocks dispatch roughly in order, so the latency-heavy atomic storm starts
// earliest and overlaps proj's MFMA work.
//   blocks [0, FILL_BLOCKS):     bucket-CSR build, 4 edges/thread
//   blocks [FILL_BLOCKS, +782):  xl = x@Wl^T+bl -> f32 (d_out),
//                                xr = x@Wr^T+br -> bf16 (ws)
// ---------------------------------------------------------------------------
__global__ __launch_bounds__(256) void mid_kernel(
    const float* __restrict__ x,
    const __hip_bfloat16* __restrict__ wswz,
    const float* __restrict__ bl, const float* __restrict__ br,
    float* __restrict__ xl, __hip_bfloat16* __restrict__ xr,
    const int* __restrict__ ei, int cap,
    int* __restrict__ cnt, uint16_t* __restrict__ csr)
{
    if (blockIdx.x < FILL_BLOCKS) {
        // ----- CSR fill: 4 edges per thread, independent atomics -----
        const uint32_t* eiw = (const uint32_t*)ei;
        bool z = (eiw[2 * (threadIdx.x & 63) + 1] == 0u);
        bool is64 = __popcll(__ballot(z)) >= 32;

        int tid = blockIdx.x * 256 + threadIdx.x;
        int e0 = tid * E_PER;
        if (e0 >= N_EDGES) return;   // 800000 % 4 == 0: no partial batches

        int src[E_PER], tgt[E_PER];
        if (is64) {
            // 4 edges = 8 dwords (low/high interleaved), 32B-aligned
            const int4* ps = (const int4*)(eiw + 2 * (size_t)e0);
            const int4* pt = (const int4*)(eiw + 2 * ((size_t)N_EDGES + e0));
#pragma unroll
            for (int k = 0; k < 2; ++k) {
                int4 s = ps[k], t = pt[k];
                src[2 * k] = s.x; src[2 * k + 1] = s.z;
                tgt[2 * k] = t.x; tgt[2 * k + 1] = t.z;
            }
        } else {
            int4 s = *(const int4*)(ei + e0);
            int4 t = *(const int4*)(ei + N_EDGES + e0);
            src[0] = s.x; src[1] = s.y; src[2] = s.z; src[3] = s.w;
            tgt[0] = t.x; tgt[1] = t.y; tgt[2] = t.z; tgt[3] = t.w;
        }

        int pos[E_PER];
#pragma unroll
        for (int k = 0; k < E_PER; ++k) {
            bool ok = (unsigned)src[k] < N_NODES && (unsigned)tgt[k] < N_NODES;
            pos[k] = ok ? atomicAdd(&cnt[tgt[k]], 1) : cap;   // cap => dropped below
        }
#pragma unroll
        for (int k = 0; k < E_PER; ++k)
            if (pos[k] < cap) csr[(size_t)tgt[k] * cap + pos[k]] = (uint16_t)src[k];
    } else {
        // ----- projection -----
        int wave = (blockIdx.x - FILL_BLOCKS) * 4 + (threadIdx.x >> 6);
        int rowbase = wave * 16;
        if (rowbase >= N_NODES) return;
        int lane = threadIdx.x & 63;
        int m = lane & 15;        // A row / B col within tile
        int quad = lane >> 4;     // k-group selector

        short8 afrag[4];
        const float* xrow = x + (size_t)(rowbase + m) * IN_CH;
#pragma unroll
        for (int ch = 0; ch < 4; ++ch) {
            f32x4 p0 = *(const f32x4*)(xrow + ch * 32 + quad * 8);
            f32x4 p1 = *(const f32x4*)(xrow + ch * 32 + quad * 8 + 4);
            short8 f;
#pragma unroll
            for (int j = 0; j < 4; ++j) { f[j] = (short)f_to_bf(p0[j]); f[j + 4] = (short)f_to_bf(p1[j]); }
            afrag[ch] = f;
        }

        const short* wz = (const short*)wswz;
#pragma unroll
        for (int ct = 0; ct < 16; ++ct) {
            const float* bv = (ct < 8) ? bl : br;
            int o = ((ct & 7) << 4) + m;   // output column (0..127)
            f32x4 acc = {0.f, 0.f, 0.f, 0.f};
#pragma unroll
            for (int ch = 0; ch < 4; ++ch) {
                short8 bfrag = *(const short8*)(wz + ((size_t)(ct * 4 + ch) * 64 + lane) * 8);
                acc = __builtin_amdgcn_mfma_f32_16x16x32_bf16(afrag[ch], bfrag, acc, 0, 0, 0);
            }
            float bias_v = bv[o];
            // D layout: row = quad*4 + r, col = m   [m89-verified]
            if (ct < 8) {
#pragma unroll
                for (int r = 0; r < 4; ++r)
                    xl[(size_t)(rowbase + quad * 4 + r) * IN_CH + o] = acc[r] + bias_v;
            } else {
#pragma unroll
                for (int r = 0; r < 4; ++r)
                    xr[(size_t)(rowbase + quad * 4 + r) * IN_CH + o] = __float2bfloat16(acc[r] + bias_v);
            }
        }
    }
}

// ---------------------------------------------------------------------------
// Fused attention + aggregation: one wave per target node.
// Unguarded softmax (|t| <~ 8 << 88: exp never overflows; identical math).
// Neighbor ids preloaded to idxreg, distributed via v_readlane (SGPR-base
// gather, zero per-lane address VALU).  Score reduce = DPP sum16.
// 2 edges/iter with prefetch depth 2 (4 edges in flight per wave) — clamped
// indices make over-prefetch harmless (L2 hits, values unused).
// q read f32 from out (own row), result overwrites it (same wave, RAW-safe).
// ---------------------------------------------------------------------------
__global__ __launch_bounds__(256) void agg_kernel(
    const __hip_bfloat16* __restrict__ xr,
    const int* __restrict__ cnt, const uint16_t* __restrict__ csr, int cap,
    const float* __restrict__ att, const float* __restrict__ bias,
    float* out /* holds xl on entry */)
{
    int n = blockIdx.x * 4 + (threadIdx.x >> 6);
    if (n >= N_NODES) return;
    int lane = threadIdx.x & 63;

    const uint32_t* xrw = (const uint32_t*)xr;   // 64 dwords per node row

    f32x2 qv = *(const f32x2*)(out + (size_t)n * IN_CH + 2 * lane);
    f32x2 av = *(const f32x2*)(att + 2 * lane);
    f32x2 bv = *(const f32x2*)(bias + 2 * lane);

    int deg = min(cnt[n], cap);
    const uint16_t* lst = csr + (size_t)n * cap;
    int idxreg = (int)lst[min(lane, cap - 1)];   // lanes >= deg: garbage, never selected

    // self-loop
    uint32_t u0 = xrw[(size_t)n * 64 + lane];
    float v0 = bf_lo(u0), v1 = bf_hi(u0);
    float t = sum16(lrelu(qv[0] + v0) * av[0] + lrelu(qv[1] + v1) * av[1]);
    float w = __expf(t);
    float lsum = w;
    float acc0 = w * v0, acc1 = w * v1;

    if (deg > 0) {
        int dm1 = deg - 1;
        // pipeline: pairs (i,i+1) processed; pairs (i+2,i+3) and (i+4,i+5)
        // in flight.  All indices clamped to dm1 (readlane stays in-range).
        int sA0 = __builtin_amdgcn_readlane(idxreg, 0);
        int sB0 = __builtin_amdgcn_readlane(idxreg, min(1, dm1));
        int sA1 = __builtin_amdgcn_readlane(idxreg, min(2, dm1));
        int sB1 = __builtin_amdgcn_readlane(idxreg, min(3, dm1));
        uint32_t uA0 = xrw[(size_t)sA0 * 64 + lane];
        uint32_t uB0 = xrw[(size_t)sB0 * 64 + lane];
        uint32_t uA1 = xrw[(size_t)sA1 * 64 + lane];
        uint32_t uB1 = xrw[(size_t)sB1 * 64 + lane];
        int i = 0;
        while (i + 1 < deg) {
            int sA2 = __builtin_amdgcn_readlane(idxreg, min(i + 4, dm1));
            int sB2 = __builtin_amdgcn_readlane(idxreg, min(i + 5, dm1));
            uint32_t uA2 = xrw[(size_t)sA2 * 64 + lane];
            uint32_t uB2 = xrw[(size_t)sB2 * 64 + lane];

            float a0 = bf_lo(uA0), a1 = bf_hi(uA0);
            float b0 = bf_lo(uB0), b1 = bf_hi(uB0);
            float tA = sum16(lrelu(qv[0] + a0) * av[0] + lrelu(qv[1] + a1) * av[1]);
            float tB = sum16(lrelu(qv[0] + b0) * av[0] + lrelu(qv[1] + b1) * av[1]);
            float wA = __expf(tA), wB = __expf(tB);
            lsum += wA + wB;
            acc0 += wA * a0 + wB * b0;
            acc1 += wA * a1 + wB * b1;

            uA0 = uA1; uB0 = uB1; uA1 = uA2; uB1 = uB2;
            i += 2;
        }
        if (i < deg) {   // odd tail: uA0 holds edge i (pipeline invariant)
            float a0 = bf_lo(uA0), a1 = bf_hi(uA0);
            float tA = sum16(lrelu(qv[0] + a0) * av[0] + lrelu(qv[1] + a1) * av[1]);
            float wA = __expf(tA);
            lsum += wA;
            acc0 += wA * a0;
            acc1 += wA * a1;
        }
    }

    float inv = 1.f / lsum;
    f32x2 ov;
    ov[0] = acc0 * inv + bv[0];
    ov[1] = acc1 * inv + bv[1];
    *(f32x2*)(out + (size_t)n * IN_CH + 2 * lane) = ov;
}

extern "C" void kernel_launch(void* const* d_in, const int* in_sizes, int n_in,
                              void* d_out, int out_size, void* d_ws, size_t ws_size,
                              hipStream_t stream) {
    const float* x    = (const float*)d_in[0];
    const int*   ei   = (const int*)d_in[1];
    const float* Wl   = (const float*)d_in[2];
    const float* bl   = (const float*)d_in[3];
    const float* Wr   = (const float*)d_in[4];
    const float* br   = (const float*)d_in[5];
    const float* att  = (const float*)d_in[6];
    const float* bias = (const float*)d_in[7];
    float* out = (float*)d_out;

    // workspace layout (bytes):
    //   xr   : [0, 12.8M)                 bf16 [N, 128]
    //   wswz : [12.8M, 12.8M+65536)       bf16 [4096*8]  (swizzled Wl|Wr)
    //   cnt  : [12865536, 13065536)       int  [N]
    //   csr  : [13065536, ...)            u16  [N, cap]
    // xl lives in d_out as f32 (each node's wave reads its own row first).
    const size_t CSR_BASE = 13065536;
    char* ws = (char*)d_ws;
    __hip_bfloat16* xr   = (__hip_bfloat16*)(ws);
    __hip_bfloat16* wswz = (__hip_bfloat16*)(ws + 12800000);
    int*      cnt = (int*)(ws + 12865536);
    uint16_t* csr = (uint16_t*)(ws + CSR_BASE);

    long long avail = (ws_size > CSR_BASE) ? (long long)(ws_size - CSR_BASE) : 0;
    int cap = (int)(avail / ((long long)N_NODES * 2));
    if (cap > 64) cap = 64;
    if (cap < 1)  cap = 1;

    prep_kernel<<<64, 256, 0, stream>>>(Wl, Wr, wswz, cnt);
    mid_kernel<<<FILL_BLOCKS + PROJ_BLOCKS, 256, 0, stream>>>(
        x, wswz, bl, br, out, xr, ei, cap, cnt, csr);
    agg_kernel<<<N_NODES / 4, 256, 0, stream>>>(xr, cnt, csr, cap, att, bias, out);
}

// Round 11
// 178.002 us; speedup vs baseline: 1.0916x; 1.0916x over previous
//
#include <hip/hip_runtime.h>
#include <hip/hip_bf16.h>
#include <stdint.h>

#define N_NODES 50000
#define N_EDGES 800000
#define IN_CH   128
#define NEG_SLOPE 0.2f

#define PROJ_BLOCKS 782          // ceil(3125 wave-tiles / 4); each wave = 16 rows
#define E_PER 16                 // edges per fill thread (16 independent atomic chains)
#define FILL_BLOCKS 196          // 50000 threads x 16 = 800000 edges exactly

typedef short short8 __attribute__((ext_vector_type(8)));
typedef float f32x4  __attribute__((ext_vector_type(4)));
typedef float f32x2  __attribute__((ext_vector_type(2)));

static __device__ __forceinline__ float bf_lo(uint32_t p) { return __uint_as_float(p << 16); }
static __device__ __forceinline__ float bf_hi(uint32_t p) { return __uint_as_float(p & 0xffff0000u); }
static __device__ __forceinline__ uint16_t f_to_bf(float f) {
    uint32_t u = __float_as_uint(f);
    u += 0x7fffu + ((u >> 16) & 1u);   // round-to-nearest-even
    return (uint16_t)(u >> 16);
}
static __device__ __forceinline__ float lrelu(float x) { return fmaxf(x, NEG_SLOPE * x); }

// 16-lane sum-broadcast, pure VALU via DPP butterfly — every lane ends with
// the full 16-lane (head-group) sum.  No LDS traffic.
static __device__ __forceinline__ float sum16(float x) {
    x += __uint_as_float(__builtin_amdgcn_update_dpp(0, __float_as_uint(x), 0xB1,  0xf, 0xf, true)); // quad_perm[1,0,3,2]
    x += __uint_as_float(__builtin_amdgcn_update_dpp(0, __float_as_uint(x), 0x4E,  0xf, 0xf, true)); // quad_perm[2,3,0,1]
    x += __uint_as_float(__builtin_amdgcn_update_dpp(0, __float_as_uint(x), 0x141, 0xf, 0xf, true)); // row_half_mirror
    x += __uint_as_float(__builtin_amdgcn_update_dpp(0, __float_as_uint(x), 0x140, 0xf, 0xf, true)); // row_mirror
    return x;
}

// ---------------------------------------------------------------------------
// prep: (a) swizzle Wl/Wr (f32) -> bf16 in MFMA B-fragment order;
//       (b) zero the cnt array (grid-stride).  One dispatch.
// ---------------------------------------------------------------------------
__global__ __launch_bounds__(256) void prep_kernel(
    const float* __restrict__ Wl, const float* __restrict__ Wr,
    __hip_bfloat16* __restrict__ wswz, int* __restrict__ cnt)
{
    int t = blockIdx.x * 256 + threadIdx.x;   // 64 blocks x 256 = 16384
    if (t < 4096) {
        int ct = t >> 8, rem = t & 255;
        int ch = rem >> 6, lane = rem & 63;
        int m = lane & 15, quad = lane >> 4;
        const float* W = (ct < 8) ? Wl : Wr;
        int o = ((ct & 7) << 4) + m;
        const float* src = W + (size_t)o * IN_CH + ch * 32 + quad * 8;
        short8 f;
#pragma unroll
        for (int j = 0; j < 8; ++j) f[j] = (short)f_to_bf(src[j]);
        *(short8*)((short*)wswz + (size_t)t * 8) = f;
    }
    for (int i = t; i < N_NODES; i += 64 * 256) cnt[i] = 0;
}

// ---------------------------------------------------------------------------
// mid: fused proj + fill (disjoint block ranges; proj first — r8-measured
// best ordering).
//   blocks [0, PROJ_BLOCKS):            xl = x@Wl^T+bl -> f32 (d_out),
//                                       xr = x@Wr^T+br -> bf16 (ws)
//   blocks [PROJ_BLOCKS, +FILL_BLOCKS): bucket-CSR build, 16 edges/thread
//                                       (16 independent atomic chains: ILP
//                                       trend 1->8->16 edges: 85->54->? us)
// ---------------------------------------------------------------------------
__global__ __launch_bounds__(256) void mid_kernel(
    const float* __restrict__ x,
    const __hip_bfloat16* __restrict__ wswz,
    const float* __restrict__ bl, const float* __restrict__ br,
    float* __restrict__ xl, __hip_bfloat16* __restrict__ xr,
    const int* __restrict__ ei, int cap,
    int* __restrict__ cnt, uint16_t* __restrict__ csr)
{
    if (blockIdx.x < PROJ_BLOCKS) {
        // ----- projection -----
        int wave = blockIdx.x * 4 + (threadIdx.x >> 6);
        int rowbase = wave * 16;
        if (rowbase >= N_NODES) return;
        int lane = threadIdx.x & 63;
        int m = lane & 15;        // A row / B col within tile
        int quad = lane >> 4;     // k-group selector

        short8 afrag[4];
        const float* xrow = x + (size_t)(rowbase + m) * IN_CH;
#pragma unroll
        for (int ch = 0; ch < 4; ++ch) {
            f32x4 p0 = *(const f32x4*)(xrow + ch * 32 + quad * 8);
            f32x4 p1 = *(const f32x4*)(xrow + ch * 32 + quad * 8 + 4);
            short8 f;
#pragma unroll
            for (int j = 0; j < 4; ++j) { f[j] = (short)f_to_bf(p0[j]); f[j + 4] = (short)f_to_bf(p1[j]); }
            afrag[ch] = f;
        }

        const short* wz = (const short*)wswz;
#pragma unroll
        for (int ct = 0; ct < 16; ++ct) {
            const float* bv = (ct < 8) ? bl : br;
            int o = ((ct & 7) << 4) + m;   // output column (0..127)
            f32x4 acc = {0.f, 0.f, 0.f, 0.f};
#pragma unroll
            for (int ch = 0; ch < 4; ++ch) {
                short8 bfrag = *(const short8*)(wz + ((size_t)(ct * 4 + ch) * 64 + lane) * 8);
                acc = __builtin_amdgcn_mfma_f32_16x16x32_bf16(afrag[ch], bfrag, acc, 0, 0, 0);
            }
            float bias_v = bv[o];
            // D layout: row = quad*4 + r, col = m   [m89-verified]
            if (ct < 8) {
#pragma unroll
                for (int r = 0; r < 4; ++r)
                    xl[(size_t)(rowbase + quad * 4 + r) * IN_CH + o] = acc[r] + bias_v;
            } else {
#pragma unroll
                for (int r = 0; r < 4; ++r)
                    xr[(size_t)(rowbase + quad * 4 + r) * IN_CH + o] = __float2bfloat16(acc[r] + bias_v);
            }
        }
    } else {
        // ----- CSR fill: 16 edges per thread, independent atomics -----
        const uint32_t* eiw = (const uint32_t*)ei;
        bool z = (eiw[2 * (threadIdx.x & 63) + 1] == 0u);
        bool is64 = __popcll(__ballot(z)) >= 32;

        int tid = (blockIdx.x - PROJ_BLOCKS) * 256 + threadIdx.x;
        if (tid >= N_EDGES / E_PER) return;   // 50000 threads exactly; no partial batches
        int e0 = tid * E_PER;

        int src[E_PER], tgt[E_PER];
        if (is64) {
            // 16 edges = 32 dwords (low/high interleaved), 64B-aligned
            const int4* ps = (const int4*)(eiw + 2 * (size_t)e0);
            const int4* pt = (const int4*)(eiw + 2 * ((size_t)N_EDGES + e0));
#pragma unroll
            for (int k = 0; k < 8; ++k) {
                int4 s = ps[k], t = pt[k];
                src[2 * k] = s.x; src[2 * k + 1] = s.z;
                tgt[2 * k] = t.x; tgt[2 * k + 1] = t.z;
            }
        } else {
            const int4* ps = (const int4*)(ei + e0);
            const int4* pt = (const int4*)(ei + N_EDGES + e0);
#pragma unroll
            for (int k = 0; k < 4; ++k) {
                int4 s = ps[k], t = pt[k];
                src[4 * k] = s.x; src[4 * k + 1] = s.y; src[4 * k + 2] = s.z; src[4 * k + 3] = s.w;
                tgt[4 * k] = t.x; tgt[4 * k + 1] = t.y; tgt[4 * k + 2] = t.z; tgt[4 * k + 3] = t.w;
            }
        }

        int pos[E_PER];
#pragma unroll
        for (int k = 0; k < E_PER; ++k) {
            bool ok = (unsigned)src[k] < N_NODES && (unsigned)tgt[k] < N_NODES;
            pos[k] = ok ? atomicAdd(&cnt[tgt[k]], 1) : cap;   // cap => dropped below
        }
#pragma unroll
        for (int k = 0; k < E_PER; ++k)
            if (pos[k] < cap) csr[(size_t)tgt[k] * cap + pos[k]] = (uint16_t)src[k];
    }
}

// ---------------------------------------------------------------------------
// Fused attention + aggregation: one wave per target node.
// Unguarded softmax (|t| <~ 8 << 88: exp never overflows; identical math).
// Neighbor ids preloaded to idxreg, distributed via v_readlane (SGPR-base
// gather, zero per-lane address VALU).  Score reduce = DPP sum16.
// 2 edges/iter, prefetch depth 2 (4 edges in flight; depth-neutral per r10 —
// gather is throughput-bound, kept because it costs nothing).
// q read f32 from out (own row), result overwrites it (same wave, RAW-safe).
// ---------------------------------------------------------------------------
__global__ __launch_bounds__(256) void agg_kernel(
    const __hip_bfloat16* __restrict__ xr,
    const int* __restrict__ cnt, const uint16_t* __restrict__ csr, int cap,
    const float* __restrict__ att, const float* __restrict__ bias,
    float* out /* holds xl on entry */)
{
    int n = blockIdx.x * 4 + (threadIdx.x >> 6);
    if (n >= N_NODES) return;
    int lane = threadIdx.x & 63;

    const uint32_t* xrw = (const uint32_t*)xr;   // 64 dwords per node row

    f32x2 qv = *(const f32x2*)(out + (size_t)n * IN_CH + 2 * lane);
    f32x2 av = *(const f32x2*)(att + 2 * lane);
    f32x2 bv = *(const f32x2*)(bias + 2 * lane);

    int deg = min(cnt[n], cap);
    const uint16_t* lst = csr + (size_t)n * cap;
    int idxreg = (int)lst[min(lane, cap - 1)];   // lanes >= deg: garbage, never selected

    // self-loop
    uint32_t u0 = xrw[(size_t)n * 64 + lane];
    float v0 = bf_lo(u0), v1 = bf_hi(u0);
    float t = sum16(lrelu(qv[0] + v0) * av[0] + lrelu(qv[1] + v1) * av[1]);
    float w = __expf(t);
    float lsum = w;
    float acc0 = w * v0, acc1 = w * v1;

    if (deg > 0) {
        int dm1 = deg - 1;
        int sA0 = __builtin_amdgcn_readlane(idxreg, 0);
        int sB0 = __builtin_amdgcn_readlane(idxreg, min(1, dm1));
        int sA1 = __builtin_amdgcn_readlane(idxreg, min(2, dm1));
        int sB1 = __builtin_amdgcn_readlane(idxreg, min(3, dm1));
        uint32_t uA0 = xrw[(size_t)sA0 * 64 + lane];
        uint32_t uB0 = xrw[(size_t)sB0 * 64 + lane];
        uint32_t uA1 = xrw[(size_t)sA1 * 64 + lane];
        uint32_t uB1 = xrw[(size_t)sB1 * 64 + lane];
        int i = 0;
        while (i + 1 < deg) {
            int sA2 = __builtin_amdgcn_readlane(idxreg, min(i + 4, dm1));
            int sB2 = __builtin_amdgcn_readlane(idxreg, min(i + 5, dm1));
            uint32_t uA2 = xrw[(size_t)sA2 * 64 + lane];
            uint32_t uB2 = xrw[(size_t)sB2 * 64 + lane];

            float a0 = bf_lo(uA0), a1 = bf_hi(uA0);
            float b0 = bf_lo(uB0), b1 = bf_hi(uB0);
            float tA = sum16(lrelu(qv[0] + a0) * av[0] + lrelu(qv[1] + a1) * av[1]);
            float tB = sum16(lrelu(qv[0] + b0) * av[0] + lrelu(qv[1] + b1) * av[1]);
            float wA = __expf(tA), wB = __expf(tB);
            lsum += wA + wB;
            acc0 += wA * a0 + wB * b0;
            acc1 += wA * a1 + wB * b1;

            uA0 = uA1; uB0 = uB1; uA1 = uA2; uB1 = uB2;
            i += 2;
        }
        if (i < deg) {   // odd tail: uA0 holds edge i (pipeline invariant)
            float a0 = bf_lo(uA0), a1 = bf_hi(uA0);
            float tA = sum16(lrelu(qv[0] + a0) * av[0] + lrelu(qv[1] + a1) * av[1]);
            float wA = __expf(tA);
            lsum += wA;
            acc0 += wA * a0;
            acc1 += wA * a1;
        }
    }

    float inv = 1.f / lsum;
    f32x2 ov;
    ov[0] = acc0 * inv + bv[0];
    ov[1] = acc1 * inv + bv[1];
    *(f32x2*)(out + (size_t)n * IN_CH + 2 * lane) = ov;
}

extern "C" void kernel_launch(void* const* d_in, const int* in_sizes, int n_in,
                              void* d_out, int out_size, void* d_ws, size_t ws_size,
                              hipStream_t stream) {
    const float* x    = (const float*)d_in[0];
    const int*   ei   = (const int*)d_in[1];
    const float* Wl   = (const float*)d_in[2];
    const float* bl   = (const float*)d_in[3];
    const float* Wr   = (const float*)d_in[4];
    const float* br   = (const float*)d_in[5];
    const float* att  = (const float*)d_in[6];
    const float* bias = (const float*)d_in[7];
    float* out = (float*)d_out;

    // workspace layout (bytes):
    //   xr   : [0, 12.8M)                 bf16 [N, 128]
    //   wswz : [12.8M, 12.8M+65536)       bf16 [4096*8]  (swizzled Wl|Wr)
    //   cnt  : [12865536, 13065536)       int  [N]
    //   csr  : [13065536, ...)            u16  [N, cap]
    // xl lives in d_out as f32 (each node's wave reads its own row first).
    const size_t CSR_BASE = 13065536;
    char* ws = (char*)d_ws;
    __hip_bfloat16* xr   = (__hip_bfloat16*)(ws);
    __hip_bfloat16* wswz = (__hip_bfloat16*)(ws + 12800000);
    int*      cnt = (int*)(ws + 12865536);
    uint16_t* csr = (uint16_t*)(ws + CSR_BASE);

    long long avail = (ws_size > CSR_BASE) ? (long long)(ws_size - CSR_BASE) : 0;
    int cap = (int)(avail / ((long long)N_NODES * 2));
    if (cap > 64) cap = 64;
    if (cap < 1)  cap = 1;

    prep_kernel<<<64, 256, 0, stream>>>(Wl, Wr, wswz, cnt);
    mid_kernel<<<PROJ_BLOCKS + FILL_BLOCKS, 256, 0, stream>>>(
        x, wswz, bl, br, out, xr, ei, cap, cnt, csr);
    agg_kernel<<<N_NODES / 4, 256, 0, stream>>>(xr, cnt, csr, cap, att, bias, out);
}